// Round 2
// baseline (393.884 us; speedup 1.0000x reference)
//
#include <hip/hip_runtime.h>

// DCI Neural-ODE battery rollout.
// B=1024 batteries, H=1024 sequential time steps.
// Mapping: 1 wave (64 lanes) per battery; lane L owns hidden units {L, L+64}
// of the 128-wide param MLP and unit L of the 64-wide resid MLP.
// Cross-lane reductions (4 params + resid) via 6-step DPP add-reduce (VALU-only).

#define NB   1024
#define HT   1024
#define HIDN 128
#define RHIDN 64

__device__ __forceinline__ float readlane_f(float v, int lane) {
    int r = __builtin_amdgcn_readlane(__builtin_bit_cast(int, v), lane);
    return __builtin_bit_cast(float, r);
}

template <int CTRL, int RMASK>
__device__ __forceinline__ float dpp_add(float x) {
    int s = __builtin_amdgcn_update_dpp(0, __builtin_bit_cast(int, x),
                                        CTRL, RMASK, 0xF, true);
    return x + __builtin_bit_cast(float, s);
}

// Full-wave (64-lane) sum, result broadcast uniform via readlane(63).
__device__ __forceinline__ float wave_sum(float x) {
    x = dpp_add<0x111, 0xF>(x);  // row_shr:1
    x = dpp_add<0x112, 0xF>(x);  // row_shr:2
    x = dpp_add<0x114, 0xF>(x);  // row_shr:4
    x = dpp_add<0x118, 0xF>(x);  // row_shr:8
    x = dpp_add<0x142, 0xA>(x);  // row_bcast:15 -> rows 1,3
    x = dpp_add<0x143, 0xC>(x);  // row_bcast:31 -> rows 2,3
    return readlane_f(x, 63);
}

__device__ __forceinline__ float tanh_fast(float x) {
    // tanh(x) = 1 - 2/(e^{2x}+1);  e^{2x} = 2^{x * 2*log2(e)}
    float t = __builtin_amdgcn_exp2f(x * 2.88539008177793f);
    float r = __builtin_amdgcn_rcpf(t + 1.0f);
    return fmaf(-2.0f, r, 1.0f);
}

__device__ __forceinline__ float softplus_fast(float x) {
    // ln(1+e^x) = ln2 * log2(1 + 2^{x*log2(e)}); inputs bounded (|x| ~< 10)
    float e = __builtin_amdgcn_exp2f(x * 1.44269504088896f);
    return 0.693147180559945f * __builtin_amdgcn_logf(e + 1.0f);
}

__global__ __launch_bounds__(64, 1) void rollout_kernel(
    const float* __restrict__ Iin, const float* __restrict__ Tzin,
    const float* __restrict__ soc0,
    const float* __restrict__ W1p, const float* __restrict__ b1p,
    const float* __restrict__ W2p, const float* __restrict__ b2p,
    const float* __restrict__ W1r, const float* __restrict__ b1r,
    const float* __restrict__ W2r, const float* __restrict__ b2r,
    float* __restrict__ out)
{
    const int b    = blockIdx.x;
    const int lane = threadIdx.x;
    const int ja = lane, jb = lane + 64;

    // ---- weights into registers (per-lane slices) ----
    const float w1pa0 = W1p[0 * HIDN + ja], w1pa1 = W1p[1 * HIDN + ja], w1pa2 = W1p[2 * HIDN + ja];
    const float w1pb0 = W1p[0 * HIDN + jb], w1pb1 = W1p[1 * HIDN + jb], w1pb2 = W1p[2 * HIDN + jb];
    const float bpa = b1p[ja], bpb = b1p[jb];
    const float w2pa0 = W2p[ja * 4 + 0], w2pa1 = W2p[ja * 4 + 1],
                w2pa2 = W2p[ja * 4 + 2], w2pa3 = W2p[ja * 4 + 3];
    const float w2pb0 = W2p[jb * 4 + 0], w2pb1 = W2p[jb * 4 + 1],
                w2pb2 = W2p[jb * 4 + 2], w2pb3 = W2p[jb * 4 + 3];
    const float w1r0 = W1r[0 * RHIDN + lane], w1r1 = W1r[1 * RHIDN + lane], w1r2 = W1r[2 * RHIDN + lane];
    const float brr  = b1r[lane];
    const float w2rr = W2r[lane];
    const float b2p0 = b2p[0], b2p1 = b2p[1], b2p2 = b2p[2], b2p3 = b2p[3];
    const float b2rr = b2r[0];

    // ---- state ----
    float socv = soc0[b];
    {   // NaN -> 0.8 (bit-pattern test: robust under fast-math)
        unsigned u = __builtin_bit_cast(unsigned, socv);
        if ((u & 0x7FFFFFFFu) > 0x7F800000u) socv = 0.8f;
    }
    float v1 = 0.0f;

    const float* Ib = Iin  + (size_t)b * HT;
    const float* Tb = Tzin + (size_t)b * HT;
    float*       Ob = out  + (size_t)b * HT;

    // prefetch first chunk of 64 time steps
    float Inext = Ib[lane];
    float Tnext = Tb[lane];

    for (int t0 = 0; t0 < HT; t0 += 64) {
        const float Ibuf = Inext;
        const float Tbuf = Tnext;
        const int t1 = t0 + 64;
        if (t1 < HT) { Inext = Ib[t1 + lane]; Tnext = Tb[t1 + lane]; }

        float Vbuf = 0.0f;
        #pragma unroll 1
        for (int s = 0; s < 64; ++s) {
            const float It = readlane_f(Ibuf, s);   // uniform (SGPR)
            const float Tt = readlane_f(Tbuf, s);

            // hidden layer, param MLP (2 units/lane)
            const float za = fmaf(Tt, w1pa2, fmaf(It, w1pa1, fmaf(socv, w1pa0, bpa)));
            const float zb = fmaf(Tt, w1pb2, fmaf(It, w1pb1, fmaf(socv, w1pb0, bpb)));
            const float ha = tanh_fast(za);
            const float hb = tanh_fast(zb);

            // partials of hp @ W2p (4 outputs)
            const float p0 = fmaf(hb, w2pb0, ha * w2pa0);
            const float p1 = fmaf(hb, w2pb1, ha * w2pa1);
            const float p2 = fmaf(hb, w2pb2, ha * w2pa2);
            const float p3 = fmaf(hb, w2pb3, ha * w2pa3);

            // resid MLP (1 unit/lane)
            const float zr  = fmaf(Tt, w1r2, fmaf(It, w1r1, fmaf(socv, w1r0, brr)));
            const float prr = tanh_fast(zr) * w2rr;

            // cross-lane reductions (5 independent DPP chains)
            const float x0    = wave_sum(p0) + b2p0;
            const float x1    = wave_sum(p1) + b2p1;
            const float x2    = wave_sum(p2) + b2p2;
            const float x3    = wave_sum(p3) + b2p3;
            const float resid = wave_sum(prr) + b2rr;

            // params (SCALES = {0.01, 0.02, 2000, 5}, EPS = 1e-6)
            const float R0 = fmaf(softplus_fast(x0), 0.01f,   1e-6f);
            const float R1 = fmaf(softplus_fast(x1), 0.02f,   1e-6f);
            const float C1 = fmaf(softplus_fast(x2), 2000.0f, 1e-6f);
            const float Q  = fmaf(softplus_fast(x3), 5.0f,    1e-6f);

            // v1' = v1 + DT*(-v1/(R1*C1) + I/C1), DT = 1
            // rcp(R1) and rcp(C1) issue in parallel; product gives 1/(R1*C1)
            const float invC1   = __builtin_amdgcn_rcpf(C1);
            const float invR1   = __builtin_amdgcn_rcpf(R1);
            const float invR1C1 = invR1 * invC1;
            v1 = v1 + fmaf(-v1, invR1C1, It * invC1);

            // soc' = clip(soc - DT*I/(Q*3600), 0, 1)
            const float invQ = __builtin_amdgcn_rcpf(Q);
            socv = fmaf(It * invQ, -2.77777777777778e-4f, socv);
            socv = fminf(fmaxf(socv, 0.0f), 1.0f);

            // V_pred = OCV(soc') - I*R0 - v1' + resid
            const float ocv = fmaf(socv, fmaf(socv, fmaf(socv, 0.3f, -0.5f), 1.2f), 3.0f);
            const float Vp  = (fmaf(-It, R0, ocv) - v1) + resid;

            Vbuf = (lane == s) ? Vp : Vbuf;  // collect for coalesced store
        }
        Ob[t0 + lane] = Vbuf;
    }
}

extern "C" void kernel_launch(void* const* d_in, const int* in_sizes, int n_in,
                              void* d_out, int out_size, void* d_ws, size_t ws_size,
                              hipStream_t stream) {
    // setup_inputs order: V(0, unused), I(1), Tz(2), soc0(3),
    // W1p(4), b1p(5), W2p(6), b2p(7), W1r(8), b1r(9), W2r(10), b2r(11)
    const float* Iin  = (const float*)d_in[1];
    const float* Tzin = (const float*)d_in[2];
    const float* soc0 = (const float*)d_in[3];
    const float* W1p  = (const float*)d_in[4];
    const float* b1p  = (const float*)d_in[5];
    const float* W2p  = (const float*)d_in[6];
    const float* b2p  = (const float*)d_in[7];
    const float* W1r  = (const float*)d_in[8];
    const float* b1r  = (const float*)d_in[9];
    const float* W2r  = (const float*)d_in[10];
    const float* b2r  = (const float*)d_in[11];
    float* out = (float*)d_out;

    hipLaunchKernelGGL(rollout_kernel, dim3(NB), dim3(64), 0, stream,
                       Iin, Tzin, soc0, W1p, b1p, W2p, b2p, W1r, b1r, W2r, b2r, out);
}

// Round 3
// 299.735 us; speedup vs baseline: 1.3141x; 1.3141x over previous
//
#include <hip/hip_runtime.h>

// DCI Neural-ODE battery rollout. B=1024 batteries, H=1024 serial steps.
// 1 wave per battery (1024 waves = 1/SIMD chip-wide). Lane L owns hidden units
// {L, L+64} of the 128-wide param MLP and unit L of the 64-wide resid MLP.
//
// Round-3 structure:
//  - packed 4-chain reduction: permlane32_swap (64->32), ds_swizzle xor16
//    (32->16), cndmask pack (chain r -> row r), shared 4-level DPP row fold.
//  - lane-split param tail: ONE softplus + scaled-fma + rcp computes all 4
//    params in parallel lane-rows; extract via 4 readlanes.
//    Rows: 0:p0->R0(x0.01)  1:p2->C1(x2000)  2:p1->R1(x0.02)  3:p3->Q(x5)

#define NB 1024
#define HT 1024
#define HIDN 128
#define RHIDN 64

typedef unsigned uint2v __attribute__((ext_vector_type(2)));

__device__ __forceinline__ float readlane_f(float v, int lane) {
    int r = __builtin_amdgcn_readlane(__builtin_bit_cast(int, v), lane);
    return __builtin_bit_cast(float, r);
}

template <int CTRL, int RMASK>
__device__ __forceinline__ float dpp_add(float x) {
    int s = __builtin_amdgcn_update_dpp(0, __builtin_bit_cast(int, x),
                                        CTRL, RMASK, 0xF, true);
    return x + __builtin_bit_cast(float, s);
}

// swap: a' = {a_lo, b_lo}, b' = {a_hi, b_hi}
__device__ __forceinline__ void permlane32_swap(float& a, float& b) {
    uint2v r = __builtin_amdgcn_permlane32_swap(
        __builtin_bit_cast(unsigned, a), __builtin_bit_cast(unsigned, b),
        false, false);
    a = __builtin_bit_cast(float, r[0]);
    b = __builtin_bit_cast(float, r[1]);
}

// lane ^= 16 (within each 32-lane half) via ds_swizzle BitMode
__device__ __forceinline__ float swz_xor16(float x) {
    int r = __builtin_amdgcn_ds_swizzle(__builtin_bit_cast(int, x), 0x401F);
    return __builtin_bit_cast(float, r);
}

// full 64-lane sum -> uniform scalar (for the single resid chain)
__device__ __forceinline__ float wave_sum(float x) {
    x = dpp_add<0x111, 0xF>(x);  // row_shr:1
    x = dpp_add<0x112, 0xF>(x);  // row_shr:2
    x = dpp_add<0x114, 0xF>(x);  // row_shr:4
    x = dpp_add<0x118, 0xF>(x);  // row_shr:8
    x = dpp_add<0x142, 0xA>(x);  // row_bcast:15
    x = dpp_add<0x143, 0xC>(x);  // row_bcast:31
    return readlane_f(x, 63);
}

__device__ __forceinline__ float tanh_fast(float x) {
    float t = __builtin_amdgcn_exp2f(x * 2.88539008177793f);   // e^{2x}
    float r = __builtin_amdgcn_rcpf(t + 1.0f);
    return fmaf(-2.0f, r, 1.0f);
}

__device__ __forceinline__ float softplus_fast(float x) {
    float e = __builtin_amdgcn_exp2f(x * 1.44269504088896f);
    return 0.693147180559945f * __builtin_amdgcn_logf(e + 1.0f);
}

__global__ __launch_bounds__(64, 1) void rollout_kernel(
    const float* __restrict__ Iin, const float* __restrict__ Tzin,
    const float* __restrict__ soc0,
    const float* __restrict__ W1p, const float* __restrict__ b1p,
    const float* __restrict__ W2p, const float* __restrict__ b2p,
    const float* __restrict__ W1r, const float* __restrict__ b1r,
    const float* __restrict__ W2r, const float* __restrict__ b2r,
    float* __restrict__ out)
{
    const int b    = blockIdx.x;
    const int lane = threadIdx.x;
    const int ja = lane, jb = lane + 64;
    const int row = lane >> 4;
    const bool oddrow = (row & 1) != 0;

    // per-lane scale constant for the lane-split param tail
    // rows: 0 -> R0 (0.01), 1 -> C1 (2000), 2 -> R1 (0.02), 3 -> Q (5)
    const float scaleLane = (row == 0) ? 0.01f : (row == 1) ? 2000.0f
                          : (row == 2) ? 0.02f : 5.0f;

    // ---- weights into registers ----
    const float w1pa0 = W1p[0 * HIDN + ja], w1pa1 = W1p[1 * HIDN + ja], w1pa2 = W1p[2 * HIDN + ja];
    const float w1pb0 = W1p[0 * HIDN + jb], w1pb1 = W1p[1 * HIDN + jb], w1pb2 = W1p[2 * HIDN + jb];
    const float bpa = b1p[ja], bpb = b1p[jb];
    const float w2pa0 = W2p[ja * 4 + 0], w2pa1 = W2p[ja * 4 + 1],
                w2pa2 = W2p[ja * 4 + 2], w2pa3 = W2p[ja * 4 + 3];
    const float w2pb0 = W2p[jb * 4 + 0], w2pb1 = W2p[jb * 4 + 1],
                w2pb2 = W2p[jb * 4 + 2], w2pb3 = W2p[jb * 4 + 3];
    const float w1r0 = W1r[0 * RHIDN + lane], w1r1 = W1r[1 * RHIDN + lane], w1r2 = W1r[2 * RHIDN + lane];
    const float brr  = b1r[lane];
    const float w2rr = W2r[lane];
    const float b2p0 = b2p[0], b2p1 = b2p[1], b2p2 = b2p[2], b2p3 = b2p[3];
    const float b2rr = b2r[0];

    // bias for the packed-reduction register, per row: {b2p0, b2p2, b2p1, b2p3}
    const float biasLane = (row == 0) ? b2p0 : (row == 1) ? b2p2
                         : (row == 2) ? b2p1 : b2p3;

    // ---- state ----
    float socv = soc0[b];
    {   unsigned u = __builtin_bit_cast(unsigned, socv);
        if ((u & 0x7FFFFFFFu) > 0x7F800000u) socv = 0.8f; }  // NaN -> 0.8
    float v1 = 0.0f;

    const float* Ib = Iin  + (size_t)b * HT;
    const float* Tb = Tzin + (size_t)b * HT;
    float*       Ob = out  + (size_t)b * HT;

    float Inext = Ib[lane];
    float Tnext = Tb[lane];

    for (int t0 = 0; t0 < HT; t0 += 64) {
        const float Ibuf = Inext;
        const float Tbuf = Tnext;
        const int t1 = t0 + 64;
        if (t1 < HT) { Inext = Ib[t1 + lane]; Tnext = Tb[t1 + lane]; }

        float Vbuf = 0.0f;
        #pragma unroll 4
        for (int s = 0; s < 64; ++s) {
            const float It = readlane_f(Ibuf, s);   // uniform (SGPR)
            const float Tt = readlane_f(Tbuf, s);

            // hidden layer, param MLP (2 units/lane)
            const float za = fmaf(Tt, w1pa2, fmaf(It, w1pa1, fmaf(socv, w1pa0, bpa)));
            const float zb = fmaf(Tt, w1pb2, fmaf(It, w1pb1, fmaf(socv, w1pb0, bpb)));
            const float ha = tanh_fast(za);
            const float hb = tanh_fast(zb);

            // per-lane partials of hp @ W2p
            float p0 = fmaf(hb, w2pb0, ha * w2pa0);
            float p1 = fmaf(hb, w2pb1, ha * w2pa1);
            float p2 = fmaf(hb, w2pb2, ha * w2pa2);
            float p3 = fmaf(hb, w2pb3, ha * w2pa3);

            // resid MLP (1 unit/lane)
            const float zr  = fmaf(Tt, w1r2, fmaf(It, w1r1, fmaf(socv, w1r0, brr)));
            const float prr = tanh_fast(zr) * w2rr;

            // ---- packed 4-chain reduction ----
            permlane32_swap(p0, p1); float ab = p0 + p1;  // lanes0-31: p0(32f), 32-63: p1(32f)
            permlane32_swap(p2, p3); float cd = p2 + p3;
            ab += swz_xor16(ab);                          // 16-fold, dup over row pairs
            cd += swz_xor16(cd);
            float z = oddrow ? cd : ab;                   // row r holds chain {p0,p2,p1,p3}[r]
            z = dpp_add<0x111, 0xF>(z);
            z = dpp_add<0x112, 0xF>(z);
            z = dpp_add<0x114, 0xF>(z);
            z = dpp_add<0x118, 0xF>(z);                   // lane 15+16r = chain-r total

            // resid reduction (independent chain, fills DPP hazard slots)
            const float resid = wave_sum(prr) + b2rr;

            // ---- lane-split param tail: 1 softplus + 1 fma + 1 rcp for all 4 ----
            const float sp   = softplus_fast(z + biasLane);
            const float par  = fmaf(sp, scaleLane, 1e-6f);
            const float ipar = __builtin_amdgcn_rcpf(par);
            const float R0    = readlane_f(par, 15);
            const float invC1 = readlane_f(ipar, 31);
            const float invR1 = readlane_f(ipar, 47);
            const float invQ  = readlane_f(ipar, 63);

            // v1' = v1 + (-v1/(R1*C1) + I/C1)
            const float invR1C1 = invR1 * invC1;
            v1 = v1 + fmaf(-v1, invR1C1, It * invC1);

            // soc' = clip(soc - I/(Q*3600), 0, 1)
            socv = fmaf(It * invQ, -2.77777777777778e-4f, socv);
            socv = fminf(fmaxf(socv, 0.0f), 1.0f);

            // V_pred = OCV(soc') - I*R0 - v1' + resid
            const float ocv = fmaf(socv, fmaf(socv, fmaf(socv, 0.3f, -0.5f), 1.2f), 3.0f);
            const float Vp  = (fmaf(-It, R0, ocv) - v1) + resid;

            Vbuf = (lane == s) ? Vp : Vbuf;
        }
        Ob[t0 + lane] = Vbuf;
    }
}

extern "C" void kernel_launch(void* const* d_in, const int* in_sizes, int n_in,
                              void* d_out, int out_size, void* d_ws, size_t ws_size,
                              hipStream_t stream) {
    // setup_inputs order: V(0, unused), I(1), Tz(2), soc0(3),
    // W1p(4), b1p(5), W2p(6), b2p(7), W1r(8), b1r(9), W2r(10), b2r(11)
    const float* Iin  = (const float*)d_in[1];
    const float* Tzin = (const float*)d_in[2];
    const float* soc0 = (const float*)d_in[3];
    const float* W1p  = (const float*)d_in[4];
    const float* b1p  = (const float*)d_in[5];
    const float* W2p  = (const float*)d_in[6];
    const float* b2p  = (const float*)d_in[7];
    const float* W1r  = (const float*)d_in[8];
    const float* b1r  = (const float*)d_in[9];
    const float* W2r  = (const float*)d_in[10];
    const float* b2r  = (const float*)d_in[11];
    float* out = (float*)d_out;

    hipLaunchKernelGGL(rollout_kernel, dim3(NB), dim3(64), 0, stream,
                       Iin, Tzin, soc0, W1p, b1p, W2p, b2p, W1r, b1r, W2r, b2r, out);
}

// Round 4
// 276.620 us; speedup vs baseline: 1.4239x; 1.0836x over previous
//
#include <hip/hip_runtime.h>

// DCI Neural-ODE battery rollout. B=1024 batteries, H=1024 serial steps.
// 2 waves per battery, chunk-lagged pipeline:
//   Wave A (serial state): param MLP -> packed 4-chain reduction -> softplus
//     tail -> soc/v1 update. Gathers {socCarry, socPost, v1, R0} per step,
//     one ds_write_b128 per 64-step chunk (double-buffered).
//   Wave B (lane = time-step, chunk c-1): resid MLP as 64 independent
//     dot-products (no cross-lane reduction), OCV + V assembly + store.
// One __syncthreads per chunk. Weights pre-scaled into exp2/log2 domain.

#define NB 1024
#define HT 1024
#define HIDN 128
#define NCHUNK 16

#define K2  2.885390081777927f   // 2*log2(e)
#define KL  1.4426950408889634f  // log2(e)
#define LN2 0.6931471805599453f

typedef unsigned uint2v __attribute__((ext_vector_type(2)));

__device__ __forceinline__ float readlane_f(float v, int lane) {
    int r = __builtin_amdgcn_readlane(__builtin_bit_cast(int, v), lane);
    return __builtin_bit_cast(float, r);
}

template <int CTRL, int RMASK>
__device__ __forceinline__ float dpp_add(float x) {
    int s = __builtin_amdgcn_update_dpp(0, __builtin_bit_cast(int, x),
                                        CTRL, RMASK, 0xF, true);
    return x + __builtin_bit_cast(float, s);
}

__device__ __forceinline__ void permlane32_swap(float& a, float& b) {
    uint2v r = __builtin_amdgcn_permlane32_swap(
        __builtin_bit_cast(unsigned, a), __builtin_bit_cast(unsigned, b),
        false, false);
    a = __builtin_bit_cast(float, r[0]);
    b = __builtin_bit_cast(float, r[1]);
}

__device__ __forceinline__ float swz_xor16(float x) {
    int r = __builtin_amdgcn_ds_swizzle(__builtin_bit_cast(int, x), 0x401F);
    return __builtin_bit_cast(float, r);
}

// tanh in pre-scaled domain: z already = 2*log2(e)*x
__device__ __forceinline__ float tanh_ps(float z) {
    float t = __builtin_amdgcn_exp2f(z);
    float r = __builtin_amdgcn_rcpf(t + 1.0f);
    return fmaf(-2.0f, r, 1.0f);
}

__global__ __launch_bounds__(128, 1) void rollout_kernel(
    const float* __restrict__ Iin, const float* __restrict__ Tzin,
    const float* __restrict__ soc0,
    const float* __restrict__ W1p, const float* __restrict__ b1p,
    const float* __restrict__ W2p, const float* __restrict__ b2p,
    const float* __restrict__ W1r, const float* __restrict__ b1r,
    const float* __restrict__ W2r, const float* __restrict__ b2r,
    float* __restrict__ out)
{
    const int b    = blockIdx.x;
    const int wid  = threadIdx.x >> 6;
    const int lane = threadIdx.x & 63;

    __shared__ float4 handBuf[2][64];  // {socCarry, socPost, v1, R0} per step
    __shared__ float4 coefS[64];       // resid MLP unit coeffs (pre-scaled)
    __shared__ float  w2rS[64];

    const float* Ib = Iin  + (size_t)b * HT;
    const float* Tb = Tzin + (size_t)b * HT;
    float*       Ob = out  + (size_t)b * HT;
    const float b2rr = b2r[0];

    // ---------------- wave-A registers ----------------
    float w1pa0=0,w1pa1=0,w1pa2=0,bpa=0, w1pb0=0,w1pb1=0,w1pb2=0,bpb=0;
    float w2pa0=0,w2pa1=0,w2pa2=0,w2pa3=0, w2pb0=0,w2pb1=0,w2pb2=0,w2pb3=0;
    float biasLane=0, scaleLane=0;
    float socv=0, v1=0, Inext=0, Tnext=0;
    const int row = lane >> 4;
    const bool oddrow = (row & 1) != 0;

    if (wid == 0) {
        const int ja = lane, jb = lane + 64;
        // hidden-layer weights pre-scaled into exp2 domain (x 2*log2e)
        w1pa0 = W1p[0*HIDN+ja]*K2; w1pa1 = W1p[1*HIDN+ja]*K2; w1pa2 = W1p[2*HIDN+ja]*K2;
        w1pb0 = W1p[0*HIDN+jb]*K2; w1pb1 = W1p[1*HIDN+jb]*K2; w1pb2 = W1p[2*HIDN+jb]*K2;
        bpa = b1p[ja]*K2; bpb = b1p[jb]*K2;
        // output-layer weights pre-scaled (x log2e) for softplus-in-log2
        w2pa0 = W2p[ja*4+0]*KL; w2pa1 = W2p[ja*4+1]*KL;
        w2pa2 = W2p[ja*4+2]*KL; w2pa3 = W2p[ja*4+3]*KL;
        w2pb0 = W2p[jb*4+0]*KL; w2pb1 = W2p[jb*4+1]*KL;
        w2pb2 = W2p[jb*4+2]*KL; w2pb3 = W2p[jb*4+3]*KL;
        // rows: 0 -> R0 (p0, x0.01), 1 -> C1 (p2, x2000), 2 -> R1 (p1, x0.02), 3 -> Q (p3, x5)
        const float b2p0 = b2p[0], b2p1 = b2p[1], b2p2 = b2p[2], b2p3 = b2p[3];
        biasLane  = ((row == 0) ? b2p0 : (row == 1) ? b2p2 : (row == 2) ? b2p1 : b2p3) * KL;
        scaleLane = ((row == 0) ? 0.01f : (row == 1) ? 2000.0f : (row == 2) ? 0.02f : 5.0f) * LN2;

        socv = soc0[b];
        unsigned u = __builtin_bit_cast(unsigned, socv);
        if ((u & 0x7FFFFFFFu) > 0x7F800000u) socv = 0.8f;   // NaN -> 0.8
        v1 = 0.0f;
        Inext = Ib[lane];
        Tnext = Tb[lane];
    }

    for (int c = 0; c <= NCHUNK; ++c) {
        if (wid == 0) {
            if (c < NCHUNK) {
                const float Ibuf = Inext;
                const float Tbuf = Tnext;
                const int t1 = (c + 1) * 64;
                if (t1 < HT) { Inext = Ib[t1 + lane]; Tnext = Tb[t1 + lane]; }

                float4 hand = make_float4(0.f, 0.f, 0.f, 0.f);
                #pragma unroll 4
                for (int s = 0; s < 64; ++s) {
                    const float It = readlane_f(Ibuf, s);
                    const float Tt = readlane_f(Tbuf, s);
                    const float carry = socv;

                    // param MLP hidden layer (pre-scaled -> exp2 domain)
                    const float za = fmaf(Tt, w1pa2, fmaf(It, w1pa1, fmaf(socv, w1pa0, bpa)));
                    const float zb = fmaf(Tt, w1pb2, fmaf(It, w1pb1, fmaf(socv, w1pb0, bpb)));
                    const float ha = tanh_ps(za);
                    const float hb = tanh_ps(zb);

                    float p0 = fmaf(hb, w2pb0, ha * w2pa0);
                    float p1 = fmaf(hb, w2pb1, ha * w2pa1);
                    float p2 = fmaf(hb, w2pb2, ha * w2pa2);
                    float p3 = fmaf(hb, w2pb3, ha * w2pa3);

                    // packed 4-chain reduction (validated round 3)
                    permlane32_swap(p0, p1); float ab = p0 + p1;
                    permlane32_swap(p2, p3); float cd = p2 + p3;
                    ab += swz_xor16(ab);
                    cd += swz_xor16(cd);
                    float z = oddrow ? cd : ab;
                    z = dpp_add<0x111, 0xF>(z);
                    z = dpp_add<0x112, 0xF>(z);
                    z = dpp_add<0x114, 0xF>(z);
                    z = dpp_add<0x118, 0xF>(z);   // lane 15+16r = chain-r total (log2 domain)

                    // softplus tail: sp = ln2*log2(exp2(z')+1), scale folded
                    const float e   = __builtin_amdgcn_exp2f(z + biasLane);
                    const float lg  = __builtin_amdgcn_logf(e + 1.0f);
                    const float par = fmaf(lg, scaleLane, 1e-6f);
                    const float ipar = __builtin_amdgcn_rcpf(par);
                    const float R0    = readlane_f(par, 15);
                    const float invC1 = readlane_f(ipar, 31);
                    const float invR1 = readlane_f(ipar, 47);
                    const float invQ  = readlane_f(ipar, 63);

                    // state update
                    const float invR1C1 = invR1 * invC1;
                    v1 = v1 + fmaf(-v1, invR1C1, It * invC1);
                    socv = fmaf(It * invQ, -2.77777777777778e-4f, socv);
                    socv = __builtin_amdgcn_fmed3f(socv, 0.0f, 1.0f);

                    // hand-off gather (lane s keeps step-s values)
                    const bool m = (lane == s);
                    hand.x = m ? carry : hand.x;
                    hand.y = m ? socv  : hand.y;
                    hand.z = m ? v1    : hand.z;
                    hand.w = m ? R0    : hand.w;
                }
                handBuf[c & 1][lane] = hand;
            }
        } else {
            if (c == 0) {
                // prologue: pack resid-MLP coefficients (pre-scaled)
                coefS[lane] = make_float4(W1r[0*64+lane]*K2, W1r[1*64+lane]*K2,
                                          W1r[2*64+lane]*K2, b1r[lane]*K2);
                w2rS[lane] = W2r[lane];
            } else {
                const int cc = c - 1;
                const float4 h  = handBuf[cc & 1][lane];
                const float  Is = Ib[cc * 64 + lane];
                const float  Ts = Tb[cc * 64 + lane];

                float acc = b2rr;
                #pragma unroll 8
                for (int j = 0; j < 64; ++j) {
                    const float4 w  = coefS[j];   // uniform addr -> LDS broadcast
                    const float  wr = w2rS[j];
                    const float z  = fmaf(Ts, w.z, fmaf(Is, w.y, fmaf(h.x, w.x, w.w)));
                    acc = fmaf(tanh_ps(z), wr, acc);
                }

                const float s1  = h.y;  // soc_new
                const float ocv = fmaf(s1, fmaf(s1, fmaf(s1, 0.3f, -0.5f), 1.2f), 3.0f);
                const float Vp  = (fmaf(-Is, h.w, ocv) - h.z) + acc;
                Ob[cc * 64 + lane] = Vp;
            }
        }
        __syncthreads();
    }
}

extern "C" void kernel_launch(void* const* d_in, const int* in_sizes, int n_in,
                              void* d_out, int out_size, void* d_ws, size_t ws_size,
                              hipStream_t stream) {
    // setup_inputs order: V(0, unused), I(1), Tz(2), soc0(3),
    // W1p(4), b1p(5), W2p(6), b2p(7), W1r(8), b1r(9), W2r(10), b2r(11)
    const float* Iin  = (const float*)d_in[1];
    const float* Tzin = (const float*)d_in[2];
    const float* soc0 = (const float*)d_in[3];
    const float* W1p  = (const float*)d_in[4];
    const float* b1p  = (const float*)d_in[5];
    const float* W2p  = (const float*)d_in[6];
    const float* b2p  = (const float*)d_in[7];
    const float* W1r  = (const float*)d_in[8];
    const float* b1r  = (const float*)d_in[9];
    const float* W2r  = (const float*)d_in[10];
    const float* b2r  = (const float*)d_in[11];
    float* out = (float*)d_out;

    hipLaunchKernelGGL(rollout_kernel, dim3(NB), dim3(128), 0, stream,
                       Iin, Tzin, soc0, W1p, b1p, W2p, b2p, W1r, b1r, W2r, b2r, out);
}

// Round 8
// 262.862 us; speedup vs baseline: 1.4984x; 1.0523x over previous
//
#include <hip/hip_runtime.h>

// DCI Neural-ODE battery rollout. B=1024 batteries, H=1024 serial steps.
// 2 waves per battery, chunk-lagged pipeline:
//   Wave A (serial state): param MLP -> packed reduction (permlane32_swap
//     folds + dual 4-level DPP row folds + row_bcast15) -> DUAL softplus tail
//     (chains {R0,R1} in ab, {C1,Q} in cd; independent => no extra latency)
//     -> soc/v1 update. Hands {socCarry, socPost, v1, R0} per step via LDS.
//   Wave B (lane = time-step, chunk c-1): resid MLP as 64 independent
//     dot-products, OCV + V assembly + store.
// All-VALU serial chain (no DS ops). Weights pre-scaled into exp2/log2 domain.

#define NB 1024
#define HT 1024
#define HIDN 128
#define NCHUNK 16

#define K2  2.885390081777927f   // 2*log2(e)
#define KL  1.4426950408889634f  // log2(e)
#define LN2 0.6931471805599453f

typedef unsigned uint2v __attribute__((ext_vector_type(2)));

__device__ __forceinline__ float readlane_f(float v, int lane) {
    int r = __builtin_amdgcn_readlane(__builtin_bit_cast(int, v), lane);
    return __builtin_bit_cast(float, r);
}

template <int CTRL, int RMASK>
__device__ __forceinline__ float dpp_add(float x) {
    int s = __builtin_amdgcn_update_dpp(0, __builtin_bit_cast(int, x),
                                        CTRL, RMASK, 0xF, true);
    return x + __builtin_bit_cast(float, s);
}

// a' = {a.lo32, b.lo32}, b' = {a.hi32, b.hi32}   (validated R3/R4)
__device__ __forceinline__ void permlane32_swap(float& a, float& b) {
    uint2v r = __builtin_amdgcn_permlane32_swap(
        __builtin_bit_cast(unsigned, a), __builtin_bit_cast(unsigned, b),
        false, false);
    a = __builtin_bit_cast(float, r[0]);
    b = __builtin_bit_cast(float, r[1]);
}

// tanh in pre-scaled domain: z already = 2*log2(e)*x
__device__ __forceinline__ float tanh_ps(float z) {
    float t = __builtin_amdgcn_exp2f(z);
    float r = __builtin_amdgcn_rcpf(t + 1.0f);
    return fmaf(-2.0f, r, 1.0f);
}

__global__ __launch_bounds__(128, 1) void rollout_kernel(
    const float* __restrict__ Iin, const float* __restrict__ Tzin,
    const float* __restrict__ soc0,
    const float* __restrict__ W1p, const float* __restrict__ b1p,
    const float* __restrict__ W2p, const float* __restrict__ b2p,
    const float* __restrict__ W1r, const float* __restrict__ b1r,
    const float* __restrict__ W2r, const float* __restrict__ b2r,
    float* __restrict__ out)
{
    const int b    = blockIdx.x;
    const int wid  = threadIdx.x >> 6;
    const int lane = threadIdx.x & 63;

    __shared__ float4 handBuf[2][64];  // {socCarry, socPost, v1, R0} per step
    __shared__ float4 coefS[64];       // resid MLP unit coeffs (pre-scaled)
    __shared__ float  w2rS[64];

    const float* Ib = Iin  + (size_t)b * HT;
    const float* Tb = Tzin + (size_t)b * HT;
    float*       Ob = out  + (size_t)b * HT;
    const float b2rr = b2r[0];

    // ---------------- wave-A registers ----------------
    float w1pa0=0,w1pa1=0,w1pa2=0,bpa=0, w1pb0=0,w1pb1=0,w1pb2=0,bpb=0;
    float w2pa0=0,w2pa1=0,w2pa2=0,w2pa3=0, w2pb0=0,w2pb1=0,w2pb2=0,w2pb3=0;
    float biasA=0, scaleA=0, biasB=0, scaleB=0;
    float socv=0, v1=0, Inext=0, Tnext=0;

    if (wid == 0) {
        const int ja = lane, jb = lane + 64;
        const int row = lane >> 4;
        // hidden-layer weights pre-scaled into exp2 domain (x 2*log2e)
        w1pa0 = W1p[0*HIDN+ja]*K2; w1pa1 = W1p[1*HIDN+ja]*K2; w1pa2 = W1p[2*HIDN+ja]*K2;
        w1pb0 = W1p[0*HIDN+jb]*K2; w1pb1 = W1p[1*HIDN+jb]*K2; w1pb2 = W1p[2*HIDN+jb]*K2;
        bpa = b1p[ja]*K2; bpb = b1p[jb]*K2;
        // output-layer weights pre-scaled (x log2e) for softplus-in-log2
        w2pa0 = W2p[ja*4+0]*KL; w2pa1 = W2p[ja*4+1]*KL;
        w2pa2 = W2p[ja*4+2]*KL; w2pa3 = W2p[ja*4+3]*KL;
        w2pb0 = W2p[jb*4+0]*KL; w2pb1 = W2p[jb*4+1]*KL;
        w2pb2 = W2p[jb*4+2]*KL; w2pb3 = W2p[jb*4+3]*KL;
        // After permlane32 folds: ab rows {c0_lo,c0_hi,c1_lo,c1_hi},
        //                         cd rows {c2_lo,c2_hi,c3_lo,c3_hi}.
        // ab rows 0-1 -> chain0 (R0, x0.01), rows 2-3 -> chain1 (R1, x0.02)
        // cd rows 0-1 -> chain2 (C1, x2000), rows 2-3 -> chain3 (Q, x5)
        const float b2p0 = b2p[0], b2p1 = b2p[1], b2p2 = b2p[2], b2p3 = b2p[3];
        biasA  = ((row <= 1) ? b2p0 : b2p1) * KL;
        scaleA = ((row <= 1) ? 0.01f : 0.02f) * LN2;
        biasB  = ((row <= 1) ? b2p2 : b2p3) * KL;
        scaleB = ((row <= 1) ? 2000.0f : 5.0f) * LN2;

        socv = soc0[b];
        unsigned u = __builtin_bit_cast(unsigned, socv);
        if ((u & 0x7FFFFFFFu) > 0x7F800000u) socv = 0.8f;   // NaN -> 0.8
        v1 = 0.0f;
        Inext = Ib[lane];
        Tnext = Tb[lane];
    }

    for (int c = 0; c <= NCHUNK; ++c) {
        if (wid == 0) {
            if (c < NCHUNK) {
                const float Ibuf = Inext;
                const float Tbuf = Tnext;
                const int t1 = (c + 1) * 64;
                if (t1 < HT) { Inext = Ib[t1 + lane]; Tnext = Tb[t1 + lane]; }

                float4 hand = make_float4(0.f, 0.f, 0.f, 0.f);
                #pragma unroll 8
                for (int s = 0; s < 64; ++s) {
                    const float It = readlane_f(Ibuf, s);
                    const float Tt = readlane_f(Tbuf, s);
                    const float ItK = It * -2.77777777777778e-4f;  // off-chain hoist
                    const float carry = socv;

                    // param MLP hidden layer (pre-scaled -> exp2 domain)
                    const float za = fmaf(Tt, w1pa2, fmaf(It, w1pa1, fmaf(socv, w1pa0, bpa)));
                    const float zb = fmaf(Tt, w1pb2, fmaf(It, w1pb1, fmaf(socv, w1pb0, bpb)));
                    const float ha = tanh_ps(za);
                    const float hb = tanh_ps(zb);

                    float p0 = fmaf(hb, w2pb0, ha * w2pa0);
                    float p1 = fmaf(hb, w2pb1, ha * w2pa1);
                    float p2 = fmaf(hb, w2pb2, ha * w2pa2);
                    float p3 = fmaf(hb, w2pb3, ha * w2pa3);

                    // fold 64->32: ab rows {c0_lo,c0_hi,c1_lo,c1_hi}, cd {c2..c3}
                    permlane32_swap(p0, p1); float ab = p0 + p1;
                    permlane32_swap(p2, p3); float cd = p2 + p3;

                    // dual 4-level DPP row folds (independent -> ILP), then
                    // row_bcast:15 into rows 1,3: lane31 = chain total (lo+hi),
                    // lane63 = other chain total.
                    ab = dpp_add<0x111, 0xF>(ab);  cd = dpp_add<0x111, 0xF>(cd);
                    ab = dpp_add<0x112, 0xF>(ab);  cd = dpp_add<0x112, 0xF>(cd);
                    ab = dpp_add<0x114, 0xF>(ab);  cd = dpp_add<0x114, 0xF>(cd);
                    ab = dpp_add<0x118, 0xF>(ab);  cd = dpp_add<0x118, 0xF>(cd);
                    ab = dpp_add<0x142, 0xA>(ab);  cd = dpp_add<0x142, 0xA>(cd);
                    // ab: lane31 = chain0 (R0), lane63 = chain1 (R1)
                    // cd: lane31 = chain2 (C1), lane63 = chain3 (Q)

                    // dual softplus tail (parallel paths, same latency as one)
                    const float eA   = __builtin_amdgcn_exp2f(ab + biasA);
                    const float eB   = __builtin_amdgcn_exp2f(cd + biasB);
                    const float lgA  = __builtin_amdgcn_logf(eA + 1.0f);
                    const float lgB  = __builtin_amdgcn_logf(eB + 1.0f);
                    const float parA = fmaf(lgA, scaleA, 1e-6f);
                    const float parB = fmaf(lgB, scaleB, 1e-6f);
                    const float iparA = __builtin_amdgcn_rcpf(parA);
                    const float iparB = __builtin_amdgcn_rcpf(parB);
                    const float R0    = readlane_f(parA, 31);
                    const float invR1 = readlane_f(iparA, 63);
                    const float invC1 = readlane_f(iparB, 31);
                    const float invQ  = readlane_f(iparB, 63);

                    // state update (short post-rcp chain)
                    const float invR1C1 = invR1 * invC1;
                    v1 = fmaf(-v1, invR1C1, fmaf(It, invC1, v1));
                    socv = fmaf(ItK, invQ, socv);
                    socv = __builtin_amdgcn_fmed3f(socv, 0.0f, 1.0f);

                    // hand-off gather (lane s keeps step-s values)
                    const bool m = (lane == s);
                    hand.x = m ? carry : hand.x;
                    hand.y = m ? socv  : hand.y;
                    hand.z = m ? v1    : hand.z;
                    hand.w = m ? R0    : hand.w;
                }
                handBuf[c & 1][lane] = hand;
            }
        } else {
            if (c == 0) {
                // prologue: pack resid-MLP coefficients (pre-scaled)
                coefS[lane] = make_float4(W1r[0*64+lane]*K2, W1r[1*64+lane]*K2,
                                          W1r[2*64+lane]*K2, b1r[lane]*K2);
                w2rS[lane] = W2r[lane];
            } else {
                const int cc = c - 1;
                const float4 h  = handBuf[cc & 1][lane];
                const float  Is = Ib[cc * 64 + lane];
                const float  Ts = Tb[cc * 64 + lane];

                float acc = b2rr;
                #pragma unroll 8
                for (int j = 0; j < 64; ++j) {
                    const float4 w  = coefS[j];   // uniform addr -> LDS broadcast
                    const float  wr = w2rS[j];
                    const float z  = fmaf(Ts, w.z, fmaf(Is, w.y, fmaf(h.x, w.x, w.w)));
                    acc = fmaf(tanh_ps(z), wr, acc);
                }

                const float s1  = h.y;  // soc_new
                const float ocv = fmaf(s1, fmaf(s1, fmaf(s1, 0.3f, -0.5f), 1.2f), 3.0f);
                const float Vp  = (fmaf(-Is, h.w, ocv) - h.z) + acc;
                Ob[cc * 64 + lane] = Vp;
            }
        }
        __syncthreads();
    }
}

extern "C" void kernel_launch(void* const* d_in, const int* in_sizes, int n_in,
                              void* d_out, int out_size, void* d_ws, size_t ws_size,
                              hipStream_t stream) {
    // setup_inputs order: V(0, unused), I(1), Tz(2), soc0(3),
    // W1p(4), b1p(5), W2p(6), b2p(7), W1r(8), b1r(9), W2r(10), b2r(11)
    const float* Iin  = (const float*)d_in[1];
    const float* Tzin = (const float*)d_in[2];
    const float* soc0 = (const float*)d_in[3];
    const float* W1p  = (const float*)d_in[4];
    const float* b1p  = (const float*)d_in[5];
    const float* W2p  = (const float*)d_in[6];
    const float* b2p  = (const float*)d_in[7];
    const float* W1r  = (const float*)d_in[8];
    const float* b1r  = (const float*)d_in[9];
    const float* W2r  = (const float*)d_in[10];
    const float* b2r  = (const float*)d_in[11];
    float* out = (float*)d_out;

    hipLaunchKernelGGL(rollout_kernel, dim3(NB), dim3(128), 0, stream,
                       Iin, Tzin, soc0, W1p, b1p, W2p, b2p, W1r, b1r, W2r, b2r, out);
}